// Round 9
// baseline (432.870 us; speedup 1.0000x reference)
//
#include <hip/hip_runtime.h>
#include <math.h>

typedef float v2f __attribute__((ext_vector_type(2)));

namespace {
constexpr int B = 2;
constexpr int N = 16384;
constexpr int M = 4096;
constexpr int GD = 16;
constexpr int NC = GD * GD * GD;
constexpr float GORG = -4.0f;
constexpr float GSCL = 2.0f;            // cells per unit (cell width 0.5)
constexpr int BLOCK = 1024;             // 16 waves
constexpr int TQ = 64;
constexpr int GROUPS = BLOCK / TQ;      // 16
constexpr int Q = 4;
constexpr int QPB = GROUPS * Q;         // 64 queries/block -> 512 blocks
constexpr int CAPQ = 64;                // per-query hit capacity (theta_final keeps cnt<=~25)
// workspace layout (bytes)
constexpr size_t OFF_WS4 = 0;                                   // float4[B][M]
constexpr size_t OFF_IDX = OFF_WS4 + (size_t)B * M * 16;        // u16[B][M]
constexpr size_t OFF_CS  = OFF_IDX + (size_t)B * M * 2;         // u32[B][NC+1]
constexpr size_t OFF_QP  = OFF_CS + (size_t)B * (NC + 1) * 4;   // u16[B][N]
constexpr size_t OFF_CUR = OFF_QP + (size_t)B * N * 2;          // u32[B][NC]
constexpr size_t OFF_QCUR = OFF_CUR + (size_t)B * NC * 4;       // u32[B][NC]
constexpr size_t WS_NEEDED = OFF_QCUR + (size_t)B * NC * 4;     // ~311 KB
}

struct __attribute__((aligned(16))) S2 { v2f xy; v2f zw; };

// Packed shifted d2 for two queries (R12/R4-validated sequence).
__device__ __forceinline__ v2f d2pair(S2 s, v2f m2x, v2f m2y, v2f m2z) {
  v2f acc;
  asm("v_pk_fma_f32 %0, %1, %2, %3 op_sel:[0,0,1] op_sel_hi:[0,1,1]"
      : "=v"(acc) : "v"(s.xy), "v"(m2x), "v"(s.zw));
  asm("v_pk_fma_f32 %0, %1, %2, %0 op_sel:[1,0,0] op_sel_hi:[1,1,1]"
      : "+v"(acc) : "v"(s.xy), "v"(m2y));
  asm("v_pk_fma_f32 %0, %1, %2, %0 op_sel:[0,0,0] op_sel_hi:[0,1,1]"
      : "+v"(acc) : "v"(s.zw), "v"(m2z));
  return acc;
}
// Scalar twin, bit-exact with d2pair slots (validated).
__device__ __forceinline__ float d2of(const float4 s, float m2x, float m2y, float m2z) {
  return fmaf(m2z, s.z, fmaf(m2y, s.y, fmaf(m2x, s.x, s.w)));
}

__device__ __forceinline__ int cell_clamp(float v) {
  int c = (int)floorf((v - GORG) * GSCL);
  return c < 0 ? 0 : (c > GD - 1 ? GD - 1 : c);
}
__device__ __forceinline__ int spread4(int v) {
  return (v & 1) | ((v & 2) << 2) | ((v & 4) << 4) | ((v & 8) << 6);
}

// ===================== build pipeline (grid-stride, parallel) ===============
__global__ __launch_bounds__(256) void k_hist(
    const float* __restrict__ points, const float* __restrict__ spoints,
    char* __restrict__ ws) {
  unsigned int* cur = (unsigned int*)(ws + OFF_CUR);
  unsigned int* qcur = (unsigned int*)(ws + OFF_QCUR);
  int i = blockIdx.x * 256 + threadIdx.x;
  if (i < B * M) {
    int b = i / M, j = i - b * M;
    const float* s = spoints + ((size_t)b * M + j) * 3;
    int c = (cell_clamp(s[2]) * GD + cell_clamp(s[1])) * GD + cell_clamp(s[0]);
    atomicAdd(&cur[b * NC + c], 1u);
  } else if (i < B * (M + N)) {
    int i2 = i - B * M;
    int b = i2 / N, j = i2 - b * N;
    const float* p = points + ((size_t)b * N + j) * 3;
    int mc = spread4(cell_clamp(p[0])) | (spread4(cell_clamp(p[1])) << 1) |
             (spread4(cell_clamp(p[2])) << 2);
    atomicAdd(&qcur[b * NC + mc], 1u);
  }
}

__global__ __launch_bounds__(1024) void k_scan(char* __restrict__ ws) {
  const int b = blockIdx.x;
  const int tid = (int)threadIdx.x;
  __shared__ unsigned int hist[NC];
  __shared__ unsigned int scn[1024];
  unsigned int* cur = (unsigned int*)(ws + OFF_CUR) + (size_t)b * NC;
  unsigned int* qcur = (unsigned int*)(ws + OFF_QCUR) + (size_t)b * NC;
  unsigned int* csg = (unsigned int*)(ws + OFF_CS) + (size_t)b * (NC + 1);

  auto prefix = [&]() {   // exclusive prefix of hist[NC] in place (R7-validated)
    const int c0 = tid * 4;
    unsigned v0 = hist[c0], v1 = hist[c0 + 1], v2 = hist[c0 + 2], v3 = hist[c0 + 3];
    unsigned s = v0 + v1 + v2 + v3;
    scn[tid] = s;
    __syncthreads();
    for (int off = 1; off < 1024; off <<= 1) {
      unsigned t = scn[tid];
      unsigned u = (tid >= off) ? scn[tid - off] : 0u;
      __syncthreads();
      scn[tid] = t + u;
      __syncthreads();
    }
    unsigned base = scn[tid] - s;
    hist[c0] = base; hist[c0 + 1] = base + v0;
    hist[c0 + 2] = base + v0 + v1; hist[c0 + 3] = base + v0 + v1 + v2;
    __syncthreads();
  };

  for (int i = 0; i < 4; ++i) hist[tid * 4 + i] = cur[tid * 4 + i];
  __syncthreads();
  prefix();
  for (int i = 0; i < 4; ++i) {
    csg[tid * 4 + i] = hist[tid * 4 + i];
    cur[tid * 4 + i] = hist[tid * 4 + i];
  }
  if (tid == 0) csg[NC] = (unsigned)M;
  __syncthreads();
  for (int i = 0; i < 4; ++i) hist[tid * 4 + i] = qcur[tid * 4 + i];
  __syncthreads();
  prefix();
  for (int i = 0; i < 4; ++i) qcur[tid * 4 + i] = hist[tid * 4 + i];
}

__global__ __launch_bounds__(256) void k_scatter(
    const float* __restrict__ points, const float* __restrict__ spoints,
    char* __restrict__ ws) {
  float4* ws4g = (float4*)(ws + OFF_WS4);
  unsigned short* idxg = (unsigned short*)(ws + OFF_IDX);
  unsigned short* qpg = (unsigned short*)(ws + OFF_QP);
  unsigned int* cur = (unsigned int*)(ws + OFF_CUR);
  unsigned int* qcur = (unsigned int*)(ws + OFF_QCUR);
  int i = blockIdx.x * 256 + threadIdx.x;
  if (i < B * M) {
    int b = i / M, j = i - b * M;
    const float* s = spoints + ((size_t)b * M + j) * 3;
    float x = s[0], y = s[1], z = s[2];
    int c = (cell_clamp(z) * GD + cell_clamp(y)) * GD + cell_clamp(x);
    unsigned pos = atomicAdd(&cur[b * NC + c], 1u);
    ws4g[(size_t)b * M + pos] = make_float4(x, y, z, x * x + y * y + z * z);
    idxg[(size_t)b * M + pos] = (unsigned short)j;
  } else if (i < B * (M + N)) {
    int i2 = i - B * M;
    int b = i2 / N, j = i2 - b * N;
    const float* p = points + ((size_t)b * N + j) * 3;
    int mc = spread4(cell_clamp(p[0])) | (spread4(cell_clamp(p[1])) << 1) |
             (spread4(cell_clamp(p[2])) << 2);
    unsigned pos = atomicAdd(&qcur[b * NC + mc], 1u);
    qpg[(size_t)b * N + pos] = (unsigned short)j;
  }
}

// ===================== main: staged brute (R4 machinery on pruned set) ======
// Soundness chain (R8 failure fixed): theta_stage1 (over box(kd) subset) is a
// sound upper bound on each query's true 11th-NN d2 -> kstar rings cover
// ball(theta_stage1) [clamp is non-expansive: dist(cellbox, bbox) <= true
// dist]. After full staging, theta is RECOMPUTED over the full staged set
// (theta_final <= theta_stage1, still >= true 11th), so Phase B collects
// every candidate <= theta_final; count stays ~11-25 (CAPQ=64 headroom) and
// ranks over the collected set equal global ranks. Lex key (d2, orig idx)
// = reference's stable top_k.
__global__ __launch_bounds__(BLOCK, 8) void voro_main(
    const float* __restrict__ points, const char* __restrict__ ws,
    float* __restrict__ out)
{
  __shared__ float4 s4[M];                                 // 64 KiB
  __shared__ unsigned short sidx[M];                       // 8 KiB
  __shared__ __align__(16) unsigned short buf[QPB][CAPQ];  // 8 KiB (=80K total)
  // pre-Phase-B aliases into buf: all reads complete before Phase B writes
  // (barrier (B) below separates them).
  int* ibb = (int*)&buf[0][0];                  // 6 ints  @ byte 0
  float* wtheta = ((float*)&buf[0][0]) + 8;     // 16 floats @ byte 32

  const int b = blockIdx.x >> 8, tile = blockIdx.x & 255;
  const int tid = (int)threadIdx.x;
  const int wl = tid & 63, g = tid >> 6;

  const float4* __restrict__ ws4g = (const float4*)(ws + OFF_WS4);
  const unsigned short* __restrict__ idxg = (const unsigned short*)(ws + OFF_IDX);
  const unsigned int* __restrict__ csg = (const unsigned int*)(ws + OFF_CS);
  const unsigned short* __restrict__ qpg = (const unsigned short*)(ws + OFF_QP);
  const int wsbase = b * M;
  const int csbase = b * (NC + 1);

  // ---- per-wave queries via Morton-sorted perm (packed registers only)
  int orig[Q]; float pp[Q];
  v2f bmx[2], bmy[2], bmz[2];
#pragma unroll
  for (int q = 0; q < Q; ++q) {
    int n = tile * QPB + q * GROUPS + g;
    orig[q] = (int)qpg[(size_t)b * N + n];
    const float* p = points + ((size_t)b * N + orig[q]) * 3;
    float px = p[0], py = p[1], pz = p[2];
    pp[q] = px * px + py * py + pz * pz;
    if (q & 1) { bmx[q >> 1].y = -2.f * px; bmy[q >> 1].y = -2.f * py; bmz[q >> 1].y = -2.f * pz; }
    else       { bmx[q >> 1].x = -2.f * px; bmy[q >> 1].x = -2.f * py; bmz[q >> 1].x = -2.f * pz; }
  }

  // ---- bbox of the block's 64 queries (wave 0)
  if (g == 0) {
    int qn = (int)qpg[(size_t)b * N + tile * QPB + wl];
    const float* p = points + ((size_t)b * N + qn) * 3;
    float xn = p[0], yn = p[1], zn = p[2];
    float xm = xn, ym = yn, zm = zn;
#pragma unroll
    for (int lvl = 1; lvl <= 32; lvl <<= 1) {
      xn = fminf(xn, __shfl_xor(xn, lvl)); xm = fmaxf(xm, __shfl_xor(xm, lvl));
      yn = fminf(yn, __shfl_xor(yn, lvl)); ym = fmaxf(ym, __shfl_xor(ym, lvl));
      zn = fminf(zn, __shfl_xor(zn, lvl)); zm = fmaxf(zm, __shfl_xor(zm, lvl));
    }
    if (wl == 0) {
      ibb[0] = cell_clamp(xn); ibb[1] = cell_clamp(xm);
      ibb[2] = cell_clamp(yn); ibb[3] = cell_clamp(ym);
      ibb[4] = cell_clamp(zn); ibb[5] = cell_clamp(zm);
    }
  }
  __syncthreads();
  const int bx0 = ibb[0], bx1 = ibb[1], by0 = ibb[2], by1 = ibb[3],
            bz0 = ibb[4], bz1 = ibb[5];

  // ---- staging: ring k = box(k)\box(k-1) around bbox (cells staged once)
  int K = 0;
  auto stage_run = [&](unsigned stu, unsigned enu) {
    int st = (int)stu, en = (int)enu;
    en = en > M ? M : en; st = st > en ? en : st;   // corruption clamp
    int len = en - st;
    for (int i = tid; i < len; i += BLOCK) {
      s4[K + i] = ws4g[wsbase + st + i];
      sidx[K + i] = idxg[wsbase + st + i];
    }
    K += len;
  };
  auto ring = [&](int k) {
    int z0 = bz0 - k; z0 = z0 < 0 ? 0 : z0;
    int z1 = bz1 + k; z1 = z1 > GD - 1 ? GD - 1 : z1;
    int y0 = by0 - k; y0 = y0 < 0 ? 0 : y0;
    int y1 = by1 + k; y1 = y1 > GD - 1 ? GD - 1 : y1;
    for (int z = z0; z <= z1; ++z) {
      bool zedge = (k == 0) || (z < bz0 - (k - 1)) || (z > bz1 + (k - 1));
      for (int y = y0; y <= y1; ++y) {
        bool edge = zedge || (y < by0 - (k - 1)) || (y > by1 + (k - 1));
        int rb = csbase + (z * GD + y) * GD;
        if (edge) {
          int xa = bx0 - k; xa = xa < 0 ? 0 : xa;
          int xb = bx1 + k; xb = xb > GD - 1 ? GD - 1 : xb;
          stage_run(csg[rb + xa], csg[rb + xb + 1]);
        } else {
          int xl = bx0 - k;
          if (xl >= 0) stage_run(csg[rb + xl], csg[rb + xl + 1]);
          int xr = bx1 + k;
          if (xr <= GD - 1) stage_run(csg[rb + xr], csg[rb + xr + 1]);
        }
      }
    }
  };

  ring(0);
  int kd = 0;
  while (K < 128 && kd < GD - 1) { ++kd; ring(kd); }   // block-uniform
  const int K1 = K;
  const int NB1 = (K1 + 1023) >> 10;
  for (int i = tid; i < NB1 * 1024 - K1; i += BLOCK)
    s4[K1 + i] = make_float4(0.f, 0.f, 0.f, INFINITY);
  __syncthreads();
  const S2* s2v = (const S2*)s4;

  // ---- Phase A (R4 code, compile-time bi + uniform guards)
  v2f bm2[2][4];
#pragma unroll
  for (int p = 0; p < 2; ++p)
#pragma unroll
    for (int bi = 0; bi < 4; ++bi) { bm2[p][bi].x = INFINITY; bm2[p][bi].y = INFINITY; }

  auto scanA = [&](int b0, int b1) {
#pragma unroll
    for (int bi = 0; bi < 4; ++bi) {
      if (bi < b0 || bi >= b1) continue;            // uniform
#pragma unroll
      for (int hf = 0; hf < 4; ++hf) {
        S2 sv[4];
#pragma unroll
        for (int c = 0; c < 4; ++c) sv[c] = s2v[(bi * 16 + hf * 4 + c) * TQ + wl];
#pragma unroll
        for (int p = 0; p < 2; ++p) {
          v2f a0 = d2pair(sv[0], bmx[p], bmy[p], bmz[p]);
          v2f a1 = d2pair(sv[1], bmx[p], bmy[p], bmz[p]);
          v2f a2 = d2pair(sv[2], bmx[p], bmy[p], bmz[p]);
          v2f a3 = d2pair(sv[3], bmx[p], bmy[p], bmz[p]);
          float tx = fminf(fminf(a0.x, a1.x), a2.x);
          bm2[p][bi].x = fminf(fminf(tx, a3.x), bm2[p][bi].x);
          float ty = fminf(fminf(a0.y, a1.y), a2.y);
          bm2[p][bi].y = fminf(fminf(ty, a3.y), bm2[p][bi].y);
        }
      }
    }
  };
  scanA(0, NB1);

  // ---- theta machinery (R4-validated bitonic over 32 pair-minima)
  const int h = wl & 31;
  bool km[15];
  {
    int st = 0;
#pragma unroll
    for (int k = 2; k <= 32; k <<= 1)
#pragma unroll
      for (int j = 16; j > 0; j >>= 1)
        if (j < k) {
          bool up = (h & k) == 0;
          bool lower = (h & j) == 0;
          km[st++] = (lower == up);
        }
  }
  float theta[Q];
  auto compute_theta = [&]() {
    float t0[Q];
#pragma unroll
    for (int p = 0; p < 2; ++p) {
      v2f m = bm2[p][0];
#pragma unroll
      for (int bi = 1; bi < 4; ++bi) {
        m.x = fminf(m.x, bm2[p][bi].x);
        m.y = fminf(m.y, bm2[p][bi].y);
      }
      t0[2 * p] = m.x; t0[2 * p + 1] = m.y;
    }
#pragma unroll
    for (int qp = 0; qp < Q; qp += 2) {
      float a0 = fminf(t0[qp], __shfl_xor(t0[qp], 32));
      float a1 = fminf(t0[qp + 1], __shfl_xor(t0[qp + 1], 32));
      float x = (wl < 32) ? a0 : a1;
      int st = 0;
#pragma unroll
      for (int k = 2; k <= 32; k <<= 1)
#pragma unroll
        for (int j = 16; j > 0; j >>= 1)
          if (j < k) {
            float o = __shfl_xor(x, j);
            x = km[st++] ? fminf(x, o) : fmaxf(x, o);
          }
      theta[qp] = __int_as_float(__builtin_amdgcn_readlane(__float_as_int(x), 10));
      theta[qp + 1] = __int_as_float(__builtin_amdgcn_readlane(__float_as_int(x), 42));
    }
  };
  compute_theta();                                  // stage-1 theta (for kstar)

  // ---- k* from block-max true theta; stage remaining rings
  {
    float tw = -INFINITY;
#pragma unroll
    for (int q = 0; q < Q; ++q) tw = fmaxf(tw, theta[q] + pp[q]);
    if (wl == 0) wtheta[g] = tw;
  }
  __syncthreads();   // (A): fences scanA's s4 reads before stage-2 writes too
  float tmax = -INFINITY;
  for (int i = 0; i < GROUPS; ++i) tmax = fmaxf(tmax, wtheta[i]);
  int kstar;
  if (isinf(tmax)) kstar = GD - 1;
  else {
    float r = sqrtf(fmaxf(tmax, 0.0f) * 1.0005f) + 1e-3f;
    kstar = (int)floorf(2.0f * r) + 1;
    kstar = kstar > GD - 1 ? GD - 1 : kstar;
  }
  for (int k2 = kd + 1; k2 <= kstar; ++k2) ring(k2);
  const int Kf = K;
  const int NBr = (Kf + 1023) >> 10;
  for (int i = tid; i < NBr * 1024 - Kf; i += BLOCK)
    s4[Kf + i] = make_float4(0.f, 0.f, 0.f, INFINITY);
  __syncthreads();   // (B): stage-2 + padding visible; buf aliases now free
  if (Kf > K1) {
    const int bnd0 = K1 >> 10;     // rescan partially-refilled boundary batch
#pragma unroll
    for (int bi = 0; bi < 4; ++bi)
      if (bi >= bnd0 && bi < NBr) {
        bm2[0][bi].x = INFINITY; bm2[0][bi].y = INFINITY;
        bm2[1][bi].x = INFINITY; bm2[1][bi].y = INFINITY;
      }
    scanA(bnd0, NBr);
    compute_theta();               // R8-bug fix: tighten theta over FULL set
  }

  // ---- Phase B: scan all staged batches (no worklist needed at this scale)
  int cnt[Q];
#pragma unroll
  for (int q = 0; q < Q; ++q) cnt[q] = 0;

  for (int bi2 = 0; bi2 < NBr; ++bi2) {             // uniform
    unsigned hm[Q] = {0u, 0u, 0u, 0u};
#pragma unroll
    for (int hf = 0; hf < 4; ++hf) {
      S2 sv[4];
#pragma unroll
      for (int c = 0; c < 4; ++c) sv[c] = s2v[(bi2 * 16 + hf * 4 + c) * TQ + wl];
#pragma unroll
      for (int p = 0; p < 2; ++p) {
#pragma unroll
        for (int c = 0; c < 4; ++c) {
          v2f acc = d2pair(sv[c], bmx[p], bmy[p], bmz[p]);
          unsigned bit = 1u << (hf * 4 + c);
          hm[2 * p]     |= (acc.x <= theta[2 * p])     ? bit : 0u;
          hm[2 * p + 1] |= (acc.y <= theta[2 * p + 1]) ? bit : 0u;
        }
      }
    }
#pragma unroll
    for (int q = 0; q < Q; ++q) {
      const int qq = q * GROUPS + g;
      unsigned m = hm[q];
      unsigned long long bmk = __ballot(m != 0u);
      while (bmk) {                                 // uniform loop
        bool have = m != 0u;
        int k = __ffs(m) - 1;
        unsigned int lo = __builtin_amdgcn_mbcnt_lo((unsigned int)bmk, 0u);
        unsigned int pr = __builtin_amdgcn_mbcnt_hi((unsigned int)(bmk >> 32), lo);
        int pos = cnt[q] + (int)pr;
        if (have && pos < CAPQ)
          buf[qq][pos] = (unsigned short)((bi2 * 16 + k) * TQ + wl);
        cnt[q] += (int)__popcll(bmk);
        m &= m - 1u;
        bmk = __ballot(m != 0u);
      }
    }
  }

  // ---- Phase C (R4 fused-pair rank; lex key = (d2, ORIG idx) via sidx)
#pragma unroll
  for (int p = 0; p < 2; ++p) {
    const int qa = 2 * p, qb = 2 * p + 1;
    const float m2xa = bmx[p].x, m2ya = bmy[p].x, m2za = bmz[p].x;
    const float m2xb = bmx[p].y, m2yb = bmy[p].y, m2zb = bmz[p].y;
    const int qqa = qa * GROUPS + g;
    const int qqb = qb * GROUPS + g;
    int ca = cnt[qa]; ca = ca < CAPQ ? ca : CAPQ;
    int cb = cnt[qb]; cb = cb < CAPQ ? cb : CAPQ;

    bool va = wl < ca, vb = wl < cb;
    int posa = (int)buf[qqa][va ? wl : 0];
    int posb = (int)buf[qqb][vb ? wl : 0];
    float4 sa = s4[posa];
    float4 sb = s4[posb];
    float d2a = va ? d2of(sa, m2xa, m2ya, m2za) : INFINITY;
    float d2b = vb ? d2of(sb, m2xb, m2yb, m2zb) : INFINITY;
    int ida = va ? (int)sidx[posa] : 0x7fffffff;
    int idb = vb ? (int)sidx[posb] : 0x7fffffff;
    const int ba = __float_as_int(d2a);
    const int bb = __float_as_int(d2b);

    int cm = ca > cb ? ca : cb;
    int cm2 = (cm + 1) & ~1;              // <= 64, readlane idx < 64
    int ranka = 0, rankb = 0;
    for (int f = 0; f < cm2; f += 2) {
#pragma unroll
      for (int u = 0; u < 2; ++u) {
        float dfa = __int_as_float(__builtin_amdgcn_readlane(ba, f + u));
        int jfa = __builtin_amdgcn_readlane(ida, f + u);
        float dfb = __int_as_float(__builtin_amdgcn_readlane(bb, f + u));
        int jfb = __builtin_amdgcn_readlane(idb, f + u);
        ranka += ((dfa < d2a) || (dfa == d2a && jfa < ida)) ? 1 : 0;
        rankb += ((dfb < d2b) || (dfb == d2b && jfb < idb)) ? 1 : 0;
      }
    }

#pragma unroll
    for (int hq = 0; hq < 2; ++hq) {
      const int q = hq == 0 ? qa : qb;
      const int rank = hq == 0 ? ranka : rankb;
      const bool v = hq == 0 ? va : vb;
      const int pos = hq == 0 ? posa : posb;
      const float4 se = hq == 0 ? sa : sb;
      const float mx = hq == 0 ? m2xa : m2xb;
      const float my = hq == 0 ? m2ya : m2yb;
      const float mz = hq == 0 ? m2za : m2zb;

      unsigned long long cbm = __ballot(v && rank == 0);
      int cl = (int)__builtin_ctzll(cbm);
      int cpos = __builtin_amdgcn_readlane(pos, cl);
      float4 cc = s4[cpos];
      float px = -0.5f * mx, py = -0.5f * my, pz = -0.5f * mz;
      float vx = px - cc.x, vy = py - cc.y, vz = pz - cc.z;

      bool isedge = v && (rank >= 1) && (rank <= 10);
      float ex = se.x - cc.x, ey = se.y - cc.y, ez = se.z - cc.z;
      float el2 = ex * ex;
      el2 = fmaf(ey, ey, el2);
      el2 = fmaf(ez, ez, el2);
      float dv = vx * ex;
      dv = fmaf(vy, ey, dv);
      dv = fmaf(vz, ez, dv);
      float tt = fmaf(-0.5f, el2, dv);
      float sq = tt * tt * __builtin_amdgcn_rcpf(el2);
      float best = isedge ? sq : INFINITY;
#pragma unroll
      for (int lvl = 1; lvl <= 32; lvl <<= 1)
        best = fminf(best, __shfl_xor(best, lvl));
      if (wl == 0) out[(size_t)b * N + orig[q]] = best;
    }
  }
}

// ===================== fallback: R4-validated brute kernel (84.2us) =========
namespace br {
constexpr int CAP = 48;
constexpr int CAPW = 256;
constexpr int NB = 4;

__global__ __launch_bounds__(BLOCK, 8) void voroloss_kernel(
    const float* __restrict__ points,
    const float* __restrict__ spoints,
    float* __restrict__ out)
{
  __shared__ float4 s4[M];
  __shared__ unsigned short wl_lds[GROUPS][CAPW];
  __shared__ __align__(16) unsigned short buf[QPB][CAP];

  const int blocks_per_batch = N / QPB;
  const int b = blockIdx.x / blocks_per_batch;
  const int tile = blockIdx.x % blocks_per_batch;
  const int tid = (int)threadIdx.x;
  const int wl = tid & 63;
  const int g = tid >> 6;

  const float* sp = spoints + (size_t)b * M * 3;
  for (int j = tid; j < M; j += BLOCK) {
    float x = sp[j * 3 + 0], y = sp[j * 3 + 1], z = sp[j * 3 + 2];
    s4[j] = make_float4(x, y, z, x * x + y * y + z * z);
  }

  float m2x[Q], m2y[Q], m2z[Q];
#pragma unroll
  for (int q = 0; q < Q; ++q) {
    int n = tile * QPB + q * GROUPS + g;
    m2x[q] = -2.0f * points[((size_t)b * N + n) * 3 + 0];
    m2y[q] = -2.0f * points[((size_t)b * N + n) * 3 + 1];
    m2z[q] = -2.0f * points[((size_t)b * N + n) * 3 + 2];
  }
  v2f bmx[2], bmy[2], bmz[2];
#pragma unroll
  for (int p = 0; p < 2; ++p) {
    bmx[p].x = m2x[2 * p]; bmx[p].y = m2x[2 * p + 1];
    bmy[p].x = m2y[2 * p]; bmy[p].y = m2y[2 * p + 1];
    bmz[p].x = m2z[2 * p]; bmz[p].y = m2z[2 * p + 1];
  }
  __syncthreads();
  const S2* s2 = (const S2*)s4;

  v2f bm2[2][NB];
#pragma unroll
  for (int p = 0; p < 2; ++p)
#pragma unroll
    for (int bi = 0; bi < NB; ++bi) { bm2[p][bi].x = INFINITY; bm2[p][bi].y = INFINITY; }

#pragma unroll
  for (int bi = 0; bi < NB; ++bi) {
#pragma unroll
    for (int hf = 0; hf < 4; ++hf) {
      S2 sv[4];
#pragma unroll
      for (int c = 0; c < 4; ++c) sv[c] = s2[(bi * 16 + hf * 4 + c) * TQ + wl];
#pragma unroll
      for (int p = 0; p < 2; ++p) {
        v2f a0 = d2pair(sv[0], bmx[p], bmy[p], bmz[p]);
        v2f a1 = d2pair(sv[1], bmx[p], bmy[p], bmz[p]);
        v2f a2 = d2pair(sv[2], bmx[p], bmy[p], bmz[p]);
        v2f a3 = d2pair(sv[3], bmx[p], bmy[p], bmz[p]);
        float tx = fminf(fminf(a0.x, a1.x), a2.x);
        bm2[p][bi].x = fminf(fminf(tx, a3.x), bm2[p][bi].x);
        float ty = fminf(fminf(a0.y, a1.y), a2.y);
        bm2[p][bi].y = fminf(fminf(ty, a3.y), bm2[p][bi].y);
      }
    }
  }
  float t0[Q];
#pragma unroll
  for (int p = 0; p < 2; ++p) {
    v2f m = bm2[p][0];
#pragma unroll
    for (int bi = 1; bi < NB; ++bi) {
      m.x = fminf(m.x, bm2[p][bi].x);
      m.y = fminf(m.y, bm2[p][bi].y);
    }
    t0[2 * p] = m.x; t0[2 * p + 1] = m.y;
  }

  const int h = wl & 31;
  bool km[15];
  {
    int st = 0;
#pragma unroll
    for (int k = 2; k <= 32; k <<= 1)
#pragma unroll
      for (int j = 16; j > 0; j >>= 1)
        if (j < k) {
          bool up = (h & k) == 0;
          bool lower = (h & j) == 0;
          km[st++] = (lower == up);
        }
  }
  float theta[Q];
#pragma unroll
  for (int qp = 0; qp < Q; qp += 2) {
    float a0 = fminf(t0[qp],     __shfl_xor(t0[qp],     32));
    float a1 = fminf(t0[qp + 1], __shfl_xor(t0[qp + 1], 32));
    float x = (wl < 32) ? a0 : a1;
    int st = 0;
#pragma unroll
    for (int k = 2; k <= 32; k <<= 1)
#pragma unroll
      for (int j = 16; j > 0; j >>= 1)
        if (j < k) {
          float o = __shfl_xor(x, j);
          x = km[st++] ? fminf(x, o) : fmaxf(x, o);
        }
    theta[qp]     = __shfl(x, 10, 64);
    theta[qp + 1] = __shfl(x, 42, 64);
  }

  int wcnt = 0;
#pragma unroll
  for (int bi = 0; bi < NB; ++bi) {
    bool hit = (bm2[0][bi].x <= theta[0]) || (bm2[0][bi].y <= theta[1]) ||
               (bm2[1][bi].x <= theta[2]) || (bm2[1][bi].y <= theta[3]);
    unsigned long long mask = __ballot(hit);
    if (mask != 0) {
      if (hit) {
        unsigned int lo = __builtin_amdgcn_mbcnt_lo((unsigned int)mask, 0u);
        unsigned int pr = __builtin_amdgcn_mbcnt_hi((unsigned int)(mask >> 32), lo);
        int pos = wcnt + (int)pr;
        if (pos < CAPW) wl_lds[g][pos] = (unsigned short)((bi << 6) | wl);
      }
      wcnt += (int)__popcll(mask);
    }
  }
  wcnt = wcnt < CAPW ? wcnt : CAPW;

  int cnt[Q];
#pragma unroll
  for (int q = 0; q < Q; ++q) cnt[q] = 0;

  for (int base = 0; base < wcnt; base += 64) {
    int ii = base + wl;
    bool val = ii < wcnt;
    int e = wl_lds[g][val ? ii : 0];
    int bi = e >> 6, src = e & 63;

    unsigned hm[Q] = {0u, 0u, 0u, 0u};
#pragma unroll
    for (int hf = 0; hf < 4; ++hf) {
      S2 sv[4];
#pragma unroll
      for (int c = 0; c < 4; ++c) sv[c] = s2[(bi * 16 + hf * 4 + c) * TQ + src];
#pragma unroll
      for (int p = 0; p < 2; ++p) {
#pragma unroll
        for (int c = 0; c < 4; ++c) {
          v2f acc = d2pair(sv[c], bmx[p], bmy[p], bmz[p]);
          unsigned bit = 1u << (hf * 4 + c);
          hm[2 * p]     |= (acc.x <= theta[2 * p])     ? bit : 0u;
          hm[2 * p + 1] |= (acc.y <= theta[2 * p + 1]) ? bit : 0u;
        }
      }
    }
    if (!val) { hm[0] = 0u; hm[1] = 0u; hm[2] = 0u; hm[3] = 0u; }

#pragma unroll
    for (int q = 0; q < Q; ++q) {
      const int qq = q * GROUPS + g;
      unsigned m = hm[q];
      unsigned long long bmk = __ballot(m != 0u);
      while (bmk) {
        bool have = m != 0u;
        int k = __ffs(m) - 1;
        unsigned int lo = __builtin_amdgcn_mbcnt_lo((unsigned int)bmk, 0u);
        unsigned int pr = __builtin_amdgcn_mbcnt_hi((unsigned int)(bmk >> 32), lo);
        int pos = cnt[q] + (int)pr;
        if (have && pos < CAP)
          buf[qq][pos] = (unsigned short)((bi * 16 + k) * TQ + src);
        cnt[q] += (int)__popcll(bmk);
        m &= m - 1u;
        bmk = __ballot(m != 0u);
      }
    }
  }

#pragma unroll
  for (int p = 0; p < 2; ++p) {
    const int qa = 2 * p, qb = 2 * p + 1;
    const int qqa = qa * GROUPS + g;
    const int qqb = qb * GROUPS + g;
    int ca = cnt[qa]; ca = ca < CAP ? ca : CAP;
    int cb = cnt[qb]; cb = cb < CAP ? cb : CAP;

    bool va = wl < ca, vb = wl < cb;
    int ida = (int)buf[qqa][va ? wl : 0];
    int idb = (int)buf[qqb][vb ? wl : 0];
    float4 sa = s4[ida];
    float4 sb = s4[idb];
    float d2a = va ? d2of(sa, m2x[qa], m2y[qa], m2z[qa]) : INFINITY;
    float d2b = vb ? d2of(sb, m2x[qb], m2y[qb], m2z[qb]) : INFINITY;
    ida = va ? ida : 0x7fffffff;
    idb = vb ? idb : 0x7fffffff;
    const int ba = __float_as_int(d2a);
    const int bb = __float_as_int(d2b);

    int cm = ca > cb ? ca : cb;
    int cm2 = (cm + 1) & ~1;
    int ranka = 0, rankb = 0;
    for (int f = 0; f < cm2; f += 2) {
#pragma unroll
      for (int u = 0; u < 2; ++u) {
        float dfa = __int_as_float(__builtin_amdgcn_readlane(ba, f + u));
        int jfa = __builtin_amdgcn_readlane(ida, f + u);
        float dfb = __int_as_float(__builtin_amdgcn_readlane(bb, f + u));
        int jfb = __builtin_amdgcn_readlane(idb, f + u);
        ranka += ((dfa < d2a) || (dfa == d2a && jfa < ida)) ? 1 : 0;
        rankb += ((dfb < d2b) || (dfb == d2b && jfb < idb)) ? 1 : 0;
      }
    }

#pragma unroll
    for (int hq = 0; hq < 2; ++hq) {
      const int q = hq == 0 ? qa : qb;
      const int rank = hq == 0 ? ranka : rankb;
      const bool v = hq == 0 ? va : vb;
      const int ide = hq == 0 ? ida : idb;
      const float4 se = hq == 0 ? sa : sb;

      unsigned long long cbm = __ballot(v && rank == 0);
      int cl = (int)__builtin_ctzll(cbm);
      int ci = __builtin_amdgcn_readlane(ide, cl);
      float4 cc = s4[ci];
      float px = -0.5f * m2x[q], py = -0.5f * m2y[q], pz = -0.5f * m2z[q];
      float vx = px - cc.x, vy = py - cc.y, vz = pz - cc.z;

      bool isedge = v && (rank >= 1) && (rank <= 10);
      float ex = se.x - cc.x, ey = se.y - cc.y, ez = se.z - cc.z;
      float el2 = ex * ex;
      el2 = fmaf(ey, ey, el2);
      el2 = fmaf(ez, ez, el2);
      float dv = vx * ex;
      dv = fmaf(vy, ey, dv);
      dv = fmaf(vz, ez, dv);
      float tt = fmaf(-0.5f, el2, dv);
      float sq = tt * tt * __builtin_amdgcn_rcpf(el2);
      float best = isedge ? sq : INFINITY;
#pragma unroll
      for (int lvl = 1; lvl <= 32; lvl <<= 1) {
        best = fminf(best, __shfl_xor(best, lvl));
      }
      if (wl == 0) out[(size_t)b * N + (tile * QPB + q * GROUPS + g)] = best;
    }
  }
}
}  // namespace br

extern "C" void kernel_launch(void* const* d_in, const int* in_sizes, int n_in,
                              void* d_out, int out_size, void* d_ws, size_t ws_size,
                              hipStream_t stream) {
  const float* points = (const float*)d_in[0];
  const float* spoints = (const float*)d_in[1];
  float* out = (float*)d_out;
  (void)in_sizes; (void)n_in; (void)out_size;
  if (d_ws != nullptr && ws_size >= WS_NEEDED) {
    char* ws = (char*)d_ws;
    hipMemsetAsync(ws + OFF_CUR, 0, (size_t)2 * B * NC * 4, stream);
    int nth = B * (M + N);
    k_hist<<<dim3((nth + 255) / 256), dim3(256), 0, stream>>>(points, spoints, ws);
    k_scan<<<dim3(B), dim3(1024), 0, stream>>>(ws);
    k_scatter<<<dim3((nth + 255) / 256), dim3(256), 0, stream>>>(points, spoints, ws);
    voro_main<<<dim3(B * (N / QPB)), dim3(BLOCK), 0, stream>>>(points, ws, out);
  } else {
    br::voroloss_kernel<<<dim3(B * (N / QPB)), dim3(BLOCK), 0, stream>>>(
        points, spoints, out);
  }
}

// Round 10
// 84.474 us; speedup vs baseline: 5.1243x; 5.1243x over previous
//
#include <hip/hip_runtime.h>
#include <math.h>

namespace {
constexpr int B = 2;
constexpr int N = 16384;
constexpr int M = 4096;
constexpr int TQ = 64;              // lanes per query group = full wave
constexpr int BLOCK = 1024;         // 16 waves/block
constexpr int Q = 4;                // queries per wave
constexpr int GROUPS = BLOCK / TQ;  // 16 waves/block
constexpr int QPB = GROUPS * Q;     // 64 queries/block -> 512 blocks = 2/CU
constexpr int NB = 4;               // batches of 16 candidates per lane
constexpr int CAP = 48;             // per-query collect capacity
constexpr int CAPW = 256;           // per-wave worklist capacity = NB*64 (exact)
}

typedef float v2f __attribute__((ext_vector_type(2)));

// LDS candidate record viewed as two VGPR pairs: (x,y) and (z,w=|s|^2).
struct __attribute__((aligned(16))) S2 { v2f xy; v2f zw; };

// Shifted squared distance for TWO queries at once via packed FP32 VOP3P.
// Slot q = fma(m2z_q, z, fma(m2y_q, y, fma(m2x_q, x, w))). (R12-validated.)
// Values shifted by -|p_q|^2: comparable ONLY within a query.
__device__ __forceinline__ v2f d2pair(S2 s, v2f m2x, v2f m2y, v2f m2z) {
  v2f acc;
  asm("v_pk_fma_f32 %0, %1, %2, %3 op_sel:[0,0,1] op_sel_hi:[0,1,1]"
      : "=v"(acc) : "v"(s.xy), "v"(m2x), "v"(s.zw));
  asm("v_pk_fma_f32 %0, %1, %2, %0 op_sel:[1,0,0] op_sel_hi:[1,1,1]"
      : "+v"(acc) : "v"(s.xy), "v"(m2y));
  asm("v_pk_fma_f32 %0, %1, %2, %0 op_sel:[0,0,0] op_sel_hi:[0,1,1]"
      : "+v"(acc) : "v"(s.zw), "v"(m2z));
  return acc;
}

// Scalar twin of d2pair's per-slot sequence — bit-exact (validated R12–R17).
__device__ __forceinline__ float d2of(const float4 s, float m2x, float m2y, float m2z) {
  return fmaf(m2z, s.z, fmaf(m2y, s.y, fmaf(m2x, s.x, s.w)));
}

// 78 KiB LDS/block, <=64 VGPR -> 2 blocks/CU, 32 waves/CU = 8 waves/SIMD.
// R1 lesson: kernel is latency/VALU-bound; max occupancy (32 waves/CU = chip
// max) beats halved-DS-traffic Q=8 by 25%. R9 lesson: grid pruning cannot
// amortize its ~39us build overhead at M=4096; this brute structure at max
// occupancy with ~68% VALUBusy is the verified best (84.2us total).
__global__ __launch_bounds__(BLOCK, 8) void voroloss_kernel(
    const float* __restrict__ points,    // [B, N, 3]
    const float* __restrict__ spoints,   // [B, M, 3]
    float* __restrict__ out)             // [B, N]
{
  __shared__ float4 s4[M];                                    // 64 KiB
  __shared__ unsigned short wl_lds[GROUPS][CAPW];             // 8 KiB
  __shared__ __align__(16) unsigned short buf[QPB][CAP];      // 6 KiB

  const int blocks_per_batch = N / QPB;      // 256
  const int b = blockIdx.x / blocks_per_batch;
  const int tile = blockIdx.x % blocks_per_batch;
  const int tid = (int)threadIdx.x;
  const int wl = tid & 63;
  const int g = tid >> 6;

  const float* sp = spoints + (size_t)b * M * 3;
  for (int j = tid; j < M; j += BLOCK) {
    float x = sp[j * 3 + 0], y = sp[j * 3 + 1], z = sp[j * 3 + 2];
    s4[j] = make_float4(x, y, z, x * x + y * y + z * z);
  }

  // Query loads hoisted ABOVE the barrier: 12 independent global loads
  // issue while the staging ds_writes drain (hides L2/HBM latency).
  float m2x[Q], m2y[Q], m2z[Q];
#pragma unroll
  for (int q = 0; q < Q; ++q) {
    int n = tile * QPB + q * GROUPS + g;     // uniform per wave
    m2x[q] = -2.0f * points[((size_t)b * N + n) * 3 + 0];
    m2y[q] = -2.0f * points[((size_t)b * N + n) * 3 + 1];
    m2z[q] = -2.0f * points[((size_t)b * N + n) * 3 + 2];
  }
  v2f bmx[2], bmy[2], bmz[2];
#pragma unroll
  for (int p = 0; p < 2; ++p) {
    bmx[p].x = m2x[2 * p]; bmx[p].y = m2x[2 * p + 1];
    bmy[p].x = m2y[2 * p]; bmy[p].y = m2y[2 * p + 1];
    bmz[p].x = m2z[2 * p]; bmz[p].y = m2z[2 * p + 1];
  }
  __syncthreads();
  const S2* s2 = (const S2*)s4;

  // ---- Phase A: per-query batch minima over NB=4 batches of 16 cands.
  v2f bm2[2][NB];
#pragma unroll
  for (int p = 0; p < 2; ++p)
#pragma unroll
    for (int bi = 0; bi < NB; ++bi) { bm2[p][bi].x = INFINITY; bm2[p][bi].y = INFINITY; }

#pragma unroll
  for (int bi = 0; bi < NB; ++bi) {
#pragma unroll
    for (int hf = 0; hf < 4; ++hf) {
      S2 sv[4];
#pragma unroll
      for (int c = 0; c < 4; ++c) sv[c] = s2[(bi * 16 + hf * 4 + c) * TQ + wl];
#pragma unroll
      for (int p = 0; p < 2; ++p) {
        v2f a0 = d2pair(sv[0], bmx[p], bmy[p], bmz[p]);
        v2f a1 = d2pair(sv[1], bmx[p], bmy[p], bmz[p]);
        v2f a2 = d2pair(sv[2], bmx[p], bmy[p], bmz[p]);
        v2f a3 = d2pair(sv[3], bmx[p], bmy[p], bmz[p]);
        float tx = fminf(fminf(a0.x, a1.x), a2.x);            // v_min3
        bm2[p][bi].x = fminf(fminf(tx, a3.x), bm2[p][bi].x);  // v_min3
        float ty = fminf(fminf(a0.y, a1.y), a2.y);
        bm2[p][bi].y = fminf(fminf(ty, a3.y), bm2[p][bi].y);
      }
    }
  }
  float t0[Q];
#pragma unroll
  for (int p = 0; p < 2; ++p) {
    v2f m = bm2[p][0];
#pragma unroll
    for (int bi = 1; bi < NB; ++bi) {
      m.x = fminf(m.x, bm2[p][bi].x);
      m.y = fminf(m.y, bm2[p][bi].y);
    }
    t0[2 * p] = m.x; t0[2 * p + 1] = m.y;
  }

  // ---- theta: 11th smallest of 32 pair-minima per query (sound upper bound
  // on the true 11th smallest; within-query so the shift cancels).
  const int h = wl & 31;
  bool km[15];
  {
    int st = 0;
#pragma unroll
    for (int k = 2; k <= 32; k <<= 1)
#pragma unroll
      for (int j = 16; j > 0; j >>= 1)
        if (j < k) {
          bool up = (h & k) == 0;
          bool lower = (h & j) == 0;
          km[st++] = (lower == up);
        }
  }
  float theta[Q];
#pragma unroll
  for (int qp = 0; qp < Q; qp += 2) {
    float a0 = fminf(t0[qp],     __shfl_xor(t0[qp],     32));
    float a1 = fminf(t0[qp + 1], __shfl_xor(t0[qp + 1], 32));
    float x = (wl < 32) ? a0 : a1;
    int st = 0;
#pragma unroll
    for (int k = 2; k <= 32; k <<= 1)
#pragma unroll
      for (int j = 16; j > 0; j >>= 1)
        if (j < k) {
          float o = __shfl_xor(x, j);
          x = km[st++] ? fminf(x, o) : fmaxf(x, o);
        }
    theta[qp]     = __shfl(x, 10, 64);
    theta[qp + 1] = __shfl(x, 42, 64);
  }

  // ---- Worklist: batches with ANY per-query hit (within-query comparison).
  int wcnt = 0;
#pragma unroll
  for (int bi = 0; bi < NB; ++bi) {
    bool hit = (bm2[0][bi].x <= theta[0]) || (bm2[0][bi].y <= theta[1]) ||
               (bm2[1][bi].x <= theta[2]) || (bm2[1][bi].y <= theta[3]);
    unsigned long long mask = __ballot(hit);
    if (mask != 0) {
      if (hit) {
        unsigned int lo = __builtin_amdgcn_mbcnt_lo((unsigned int)mask, 0u);
        unsigned int pr = __builtin_amdgcn_mbcnt_hi((unsigned int)(mask >> 32), lo);
        int pos = wcnt + (int)pr;
        if (pos < CAPW) wl_lds[g][pos] = (unsigned short)((bi << 6) | wl);
      }
      wcnt += (int)__popcll(mask);
    }
  }
  wcnt = wcnt < CAPW ? wcnt : CAPW;

  // ---- Phase B-lite: re-evaluate worklist batches. Per-lane 16-bit hit
  // masks, then one ffbl flush loop per query (usually 1 iteration).
  int cnt[Q];
#pragma unroll
  for (int q = 0; q < Q; ++q) cnt[q] = 0;

  for (int base = 0; base < wcnt; base += 64) {
    int ii = base + wl;
    bool val = ii < wcnt;
    int e = wl_lds[g][val ? ii : 0];
    int bi = e >> 6, src = e & 63;

    unsigned hm[Q] = {0u, 0u, 0u, 0u};
#pragma unroll
    for (int hf = 0; hf < 4; ++hf) {
      S2 sv[4];
#pragma unroll
      for (int c = 0; c < 4; ++c) sv[c] = s2[(bi * 16 + hf * 4 + c) * TQ + src];
#pragma unroll
      for (int p = 0; p < 2; ++p) {
#pragma unroll
        for (int c = 0; c < 4; ++c) {
          v2f acc = d2pair(sv[c], bmx[p], bmy[p], bmz[p]);
          unsigned bit = 1u << (hf * 4 + c);
          hm[2 * p]     |= (acc.x <= theta[2 * p])     ? bit : 0u;
          hm[2 * p + 1] |= (acc.y <= theta[2 * p + 1]) ? bit : 0u;
        }
      }
    }
    if (!val) { hm[0] = 0u; hm[1] = 0u; hm[2] = 0u; hm[3] = 0u; }

#pragma unroll
    for (int q = 0; q < Q; ++q) {
      const int qq = q * GROUPS + g;
      unsigned m = hm[q];
      unsigned long long bmk = __ballot(m != 0u);
      while (bmk) {                       // uniform loop; ~1 iteration
        bool have = m != 0u;
        int k = __ffs(m) - 1;
        unsigned int lo = __builtin_amdgcn_mbcnt_lo((unsigned int)bmk, 0u);
        unsigned int pr = __builtin_amdgcn_mbcnt_hi((unsigned int)(bmk >> 32), lo);
        int pos = cnt[q] + (int)pr;
        if (have && pos < CAP)
          buf[qq][pos] = (unsigned short)((bi * 16 + k) * TQ + src);
        cnt[q] += (int)__popcll(bmk);
        m &= m - 1u;
        bmk = __ballot(m != 0u);
      }
    }
  }

  // ---- Phase C: exact selection (lex (d2,idx) = stable top_k).
  // Fused PAIR rank loops: one loop of max(ca,cb) iterations serves two
  // queries (4 independent readlanes/iter, unrolled x2) instead of two
  // serial loops of ca+cb iterations. Padding is safe: lanes >= c hold
  // (INF, INT_MAX) keys which contribute 0 to any valid lane's rank.
#pragma unroll
  for (int p = 0; p < 2; ++p) {
    const int qa = 2 * p, qb = 2 * p + 1;
    const int qqa = qa * GROUPS + g;
    const int qqb = qb * GROUPS + g;
    int ca = cnt[qa]; ca = ca < CAP ? ca : CAP;
    int cb = cnt[qb]; cb = cb < CAP ? cb : CAP;

    bool va = wl < ca, vb = wl < cb;
    int ida = (int)buf[qqa][va ? wl : 0];
    int idb = (int)buf[qqb][vb ? wl : 0];
    float4 sa = s4[ida];
    float4 sb = s4[idb];
    float d2a = va ? d2of(sa, m2x[qa], m2y[qa], m2z[qa]) : INFINITY;
    float d2b = vb ? d2of(sb, m2x[qb], m2y[qb], m2z[qb]) : INFINITY;
    ida = va ? ida : 0x7fffffff;
    idb = vb ? idb : 0x7fffffff;
    const int ba = __float_as_int(d2a);
    const int bb = __float_as_int(d2b);

    int cm = ca > cb ? ca : cb;
    int cm2 = (cm + 1) & ~1;              // <= CAP=48, readlane idx < 64
    int ranka = 0, rankb = 0;
    for (int f = 0; f < cm2; f += 2) {    // f wave-uniform -> readlane->SGPR
#pragma unroll
      for (int u = 0; u < 2; ++u) {
        float dfa = __int_as_float(__builtin_amdgcn_readlane(ba, f + u));
        int jfa = __builtin_amdgcn_readlane(ida, f + u);
        float dfb = __int_as_float(__builtin_amdgcn_readlane(bb, f + u));
        int jfb = __builtin_amdgcn_readlane(idb, f + u);
        ranka += ((dfa < d2a) || (dfa == d2a && jfa < ida)) ? 1 : 0;
        rankb += ((dfb < d2b) || (dfb == d2b && jfb < idb)) ? 1 : 0;
      }
    }

#pragma unroll
    for (int hq = 0; hq < 2; ++hq) {
      const int q = hq == 0 ? qa : qb;
      const int rank = hq == 0 ? ranka : rankb;
      const bool v = hq == 0 ? va : vb;
      const int ide = hq == 0 ? ida : idb;
      const float4 se = hq == 0 ? sa : sb;

      // center = rank 0 (exists, unique): ballot + readlane its index.
      unsigned long long cbm = __ballot(v && rank == 0);
      int cl = (int)__builtin_ctzll(cbm);
      int ci = __builtin_amdgcn_readlane(ide, cl);
      float4 cc = s4[ci];
      float px = -0.5f * m2x[q], py = -0.5f * m2y[q], pz = -0.5f * m2z[q];
      float vx = px - cc.x, vy = py - cc.y, vz = pz - cc.z;

      // edges = ranks 1..10 (exactly 10 since c >= 11).
      bool isedge = v && (rank >= 1) && (rank <= 10);
      float ex = se.x - cc.x, ey = se.y - cc.y, ez = se.z - cc.z;
      float el2 = ex * ex;
      el2 = fmaf(ey, ey, el2);
      el2 = fmaf(ez, ez, el2);
      float dv = vx * ex;
      dv = fmaf(vy, ey, dv);
      dv = fmaf(vz, ez, dv);
      float tt = fmaf(-0.5f, el2, dv);
      float sq = tt * tt * __builtin_amdgcn_rcpf(el2);
      float best = isedge ? sq : INFINITY;
#pragma unroll
      for (int lvl = 1; lvl <= 32; lvl <<= 1) {
        best = fminf(best, __shfl_xor(best, lvl));
      }
      if (wl == 0) out[(size_t)b * N + (tile * QPB + q * GROUPS + g)] = best;
    }
  }
}

extern "C" void kernel_launch(void* const* d_in, const int* in_sizes, int n_in,
                              void* d_out, int out_size, void* d_ws, size_t ws_size,
                              hipStream_t stream) {
  const float* points = (const float*)d_in[0];
  const float* spoints = (const float*)d_in[1];
  float* out = (float*)d_out;
  (void)in_sizes; (void)n_in; (void)out_size; (void)d_ws; (void)ws_size;
  voroloss_kernel<<<dim3(B * (N / QPB)), dim3(BLOCK), 0, stream>>>(points, spoints, out);
}